// Round 1
// baseline (218.481 us; speedup 1.0000x reference)
//
#include <hip/hip_runtime.h>

namespace {

constexpr float FF[12] = {0.0144f, 0.0272f, 0.0526f, 0.0972f, 0.193f, 0.63f,
                          -0.63f, -0.193f, -0.0972f, -0.0526f, -0.0272f, -0.0144f};
constexpr float SQ2   = 1.41421356237309515f;
constexpr float NISQ2 = -0.70710678118654752f;

// Horizontal 12-tap correlation on one LDS row (float4-grouped), periodic width W4*4.
template <int O, int W4>
__device__ __forceinline__ float4 hconv(const float4* R4, int row4, int j4) {
  float r[20];
#pragma unroll
  for (int d = 0; d < 5; ++d) {
    float4 t = R4[row4 + ((j4 + d - 2) & (W4 - 1))];
    r[4 * d + 0] = t.x; r[4 * d + 1] = t.y; r[4 * d + 2] = t.z; r[4 * d + 3] = t.w;
  }
  float4 o = make_float4(0.f, 0.f, 0.f, 0.f);
#pragma unroll
  for (int a = 0; a < 12; ++a) {
    const float fa = FF[a];
    o.x += fa * r[8 + 0 + a - O];
    o.y += fa * r[8 + 1 + a - O];
    o.z += fa * r[8 + 2 + a - O];
    o.w += fa * r[8 + 3 + a - O];
  }
  return o;
}

// Vertical 12-tap correlation, plain periodic rows (stage 1: 128 rows x 32 groups).
template <int O>
__device__ __forceinline__ float4 vconv_s1(const float4* S4, int i, int j4) {
  float4 o = make_float4(0.f, 0.f, 0.f, 0.f);
#pragma unroll
  for (int a = 0; a < 12; ++a) {
    const float fa = FF[a];
    float4 v = S4[((i + a - O) & 127) * 32 + j4];
    o.x += fa * v.x; o.y += fa * v.y; o.z += fa * v.z; o.w += fa * v.w;
  }
  return o;
}

// Vertical 12-tap correlation, qper_col rows (stage 2: 128 rows x 64 groups;
// out-of-range rows wrap with column+128 shift == group XOR 32).
template <int O>
__device__ __forceinline__ float4 vconv_s2(const float4* S4, int i, int j4) {
  float4 o = make_float4(0.f, 0.f, 0.f, 0.f);
#pragma unroll
  for (int a = 0; a < 12; ++a) {
    const float fa = FF[a];
    int r = i + a - O;
    int idx = ((unsigned)r < 128u) ? (r * 64 + j4) : ((r & 127) * 64 + (j4 ^ 32));
    float4 v = S4[idx];
    o.x += fa * v.x; o.y += fa * v.y; o.z += fa * v.z; o.w += fa * v.w;
  }
  return o;
}

// Stage-1 plane: fbrec(Y0, Y1, '2c', 'per') for one 128x128 channel pair.
// Result x-plane (128x256 fp32) is left in xv[8] registers per thread,
// indexed xv[k] <-> float4 group t = tid + k*1024 (exactly the layout stage-2
// consumes).  Uses bufA/bufB (64 KiB each); exits with a trailing barrier so
// the caller may immediately reuse LDS.
__device__ __forceinline__ void s1_plane(const float4* __restrict__ Y04,
                                         const float4* __restrict__ Y14,
                                         float* __restrict__ bufA,
                                         float* __restrict__ bufB,
                                         float4* __restrict__ xv, int tid) {
  float4* A4 = reinterpret_cast<float4*>(bufA);
  float4* B4 = reinterpret_cast<float4*>(bufB);

  // 1. load Y0 plane -> A
#pragma unroll
  for (int k = 0; k < 4; ++k) A4[tid + k * 1024] = Y04[tid + k * 1024];
  __syncthreads();

  // 2. B = vert conv offset-5 of Y0
#pragma unroll
  for (int k = 0; k < 4; ++k) {
    int g = tid + k * 1024;
    B4[g] = vconv_s1<5>(A4, g >> 5, g & 31);
  }
  __syncthreads();

  // 3. A = p1 = -1/sqrt2 * (Y1 + horz conv offset-5 of B)
#pragma unroll
  for (int k = 0; k < 4; ++k) {
    int g = tid + k * 1024;
    int i = g >> 5, j4 = g & 31;
    float4 h = hconv<5, 32>(B4, i * 32, j4);
    float4 yv = Y14[g];
    A4[g] = make_float4(NISQ2 * (yv.x + h.x), NISQ2 * (yv.y + h.y),
                        NISQ2 * (yv.z + h.z), NISQ2 * (yv.w + h.w));
  }
  __syncthreads();

  // 4. B = vert conv offset-6 of p1
#pragma unroll
  for (int k = 0; k < 4; ++k) {
    int g = tid + k * 1024;
    B4[g] = vconv_s1<6>(A4, g >> 5, g & 31);
  }
  __syncthreads();

  // 5. B = p0 = sqrt2*Y0 + horz conv offset-6 of B (reg-staged; Y0 reloaded from L2)
  float4 pv[4];
#pragma unroll
  for (int k = 0; k < 4; ++k) {
    int g = tid + k * 1024;
    int i = g >> 5, j4 = g & 31;
    float4 h = hconv<6, 32>(B4, i * 32, j4);
    float4 yv = Y04[g];
    pv[k] = make_float4(SQ2 * yv.x + h.x, SQ2 * yv.y + h.y,
                        SQ2 * yv.z + h.z, SQ2 * yv.w + h.w);
  }
  __syncthreads();
#pragma unroll
  for (int k = 0; k < 4; ++k) B4[tid + k * 1024] = pv[k];
  __syncthreads();

  // 6. qprec '2c' permute -> registers. x[i,jo], J=(i+jo)&255;
  //    even J -> p0[(i-J/2)&127, J/2] (B), odd J -> p1[(i-1-J/2)&127, J/2] (A).
#pragma unroll
  for (int k = 0; k < 8; ++k) {
    int t = tid + k * 1024;
    int i = t >> 6;
    int jb = (t & 63) << 2;
    float tmp[4];
#pragma unroll
    for (int m = 0; m < 4; ++m) {
      int jo = jb + m;
      int J = (i + jo) & 255;
      int c = J >> 1;
      tmp[m] = (J & 1) ? bufA[((i - 1 - c) & 127) * 128 + c]
                       : bufB[((i - c) & 127) * 128 + c];
    }
    xv[k] = make_float4(tmp[0], tmp[1], tmp[2], tmp[3]);
  }
  __syncthreads();  // permute reads done; LDS free for reuse
}

}  // namespace

// Fully fused: one block per output plane (b,c).  Stage-1 runs twice (x1 from
// y2/y3, x0 from y1/y0) with results register-carried; stage-2 consumes them
// without any HBM intermediate; output written as merged, fully-coalesced
// float4 stores (odd-I values stashed in registers while p1 is live in LDS).
__global__ __launch_bounds__(1024) void fused_kernel(
    const float* __restrict__ y0, const float* __restrict__ y1,
    const float* __restrict__ y2, const float* __restrict__ y3,
    float* __restrict__ out) {
  __shared__ float buf[32768];  // union: s1 {A,B} 64KiB each | s2 plane 128KiB
  float* bufA = buf;
  float* bufB = buf + 16384;
  float4* X4 = reinterpret_cast<float4*>(buf);

  const int q = blockIdx.x;  // 0..255 = b*32 + c
  const int tid = threadIdx.x;
  const size_t sub4 = (size_t)q * 4096;  // input plane offset in float4

  const float4* Y0a = reinterpret_cast<const float4*>(y2) + sub4;  // x1 inputs
  const float4* Y1a = reinterpret_cast<const float4*>(y3) + sub4;
  const float4* Y0b = reinterpret_cast<const float4*>(y1) + sub4;  // x0 inputs
  const float4* Y1b = reinterpret_cast<const float4*>(y0) + sub4;

  float4 xv1[8], xv0[8];
  s1_plane(Y0a, Y1a, bufA, bufB, xv1, tid);  // x1 = x[:, 32+c]
  s1_plane(Y0b, Y1b, bufA, bufB, xv0, tid);  // x0 = x[:, c]

  // ---------------- stage 2: fbrec(x0, x1, '1r', 'qper_col') ----------------
  // 1. x0 -> LDS (same linear layout the registers hold)
#pragma unroll
  for (int k = 0; k < 8; ++k) X4[tid + k * 1024] = xv0[k];
  __syncthreads();

  float4 tv[8];
  // 2. vert conv offset-5 (qper rows), in-place via full reg staging
#pragma unroll
  for (int k = 0; k < 8; ++k) {
    int g = tid + k * 1024;
    tv[k] = vconv_s2<5>(X4, g >> 6, g & 63);
  }
  __syncthreads();
#pragma unroll
  for (int k = 0; k < 8; ++k) X4[tid + k * 1024] = tv[k];
  __syncthreads();

  // 3. p1 = -1/sqrt2 * (x1 + horz conv offset-5); result overwrites xv1 slots
#pragma unroll
  for (int k = 0; k < 8; ++k) {
    int g = tid + k * 1024;
    int i = g >> 6, j4 = g & 63;
    float4 h = hconv<5, 64>(X4, i * 64, j4);
    xv1[k] = make_float4(NISQ2 * (xv1[k].x + h.x), NISQ2 * (xv1[k].y + h.y),
                         NISQ2 * (xv1[k].z + h.z), NISQ2 * (xv1[k].w + h.w));
  }
  __syncthreads();
#pragma unroll
  for (int k = 0; k < 8; ++k) X4[tid + k * 1024] = xv1[k];
  __syncthreads();

  // 3b. stash odd-I output values (permute of p1) in registers, laid out for
  //     the merged final write.  out[i,jo] = p1[r, (jo-1-r)&255], r=((i+jo)&255)>>1.
  //     Odd-I slots within the float4 at (i, jb) are m = m0, m0+2 with m0 = 1-(i&1).
  float ov[32];
#pragma unroll
  for (int k = 0; k < 16; ++k) {
    int t = tid + k * 1024;
    int i = t >> 6;
    int jb = (t & 63) << 2;
    int m0 = 1 - (i & 1);
#pragma unroll
    for (int s = 0; s < 2; ++s) {
      int jo = jb + m0 + 2 * s;
      int r = ((i + jo) & 255) >> 1;
      int cc2 = (jo - 1 - r) & 255;
      ov[2 * k + s] = buf[r * 256 + cc2];
    }
  }
  // (reads only; ordered vs. the next overwrite by the sync after step-4 compute)

  // 4. vert conv offset-6 of p1 (qper rows)
#pragma unroll
  for (int k = 0; k < 8; ++k) {
    int g = tid + k * 1024;
    tv[k] = vconv_s2<6>(X4, g >> 6, g & 63);
  }
  __syncthreads();
#pragma unroll
  for (int k = 0; k < 8; ++k) X4[tid + k * 1024] = tv[k];
  __syncthreads();

  // 5. p0 = sqrt2*x0 + horz conv offset-6; result overwrites xv0 slots
#pragma unroll
  for (int k = 0; k < 8; ++k) {
    int g = tid + k * 1024;
    int i = g >> 6, j4 = g & 63;
    float4 h = hconv<6, 64>(X4, i * 64, j4);
    xv0[k] = make_float4(SQ2 * xv0[k].x + h.x, SQ2 * xv0[k].y + h.y,
                         SQ2 * xv0[k].z + h.z, SQ2 * xv0[k].w + h.w);
  }
  __syncthreads();
#pragma unroll
  for (int k = 0; k < 8; ++k) X4[tid + k * 1024] = xv0[k];
  __syncthreads();

  // 6. merged, fully-coalesced write: even-I from p0 (LDS), odd-I from ov regs.
  //    even: out[i,jo] = p0[r, (jo-r)&255], r=((i+jo)&255)>>1.
  float4* op4 = reinterpret_cast<float4*>(out) + (size_t)q * 16384;
#pragma unroll
  for (int k = 0; k < 16; ++k) {
    int t = tid + k * 1024;
    int i = t >> 6;
    int jb = (t & 63) << 2;
    float4 v;
    if (i & 1) {  // odd-I at m=0,2; even-I at m=1,3  (wave-uniform branch)
      int jo1 = jb + 1, jo3 = jb + 3;
      int r1 = ((i + jo1) & 255) >> 1;
      int r3 = ((i + jo3) & 255) >> 1;
      v.x = ov[2 * k];
      v.y = buf[r1 * 256 + ((jo1 - r1) & 255)];
      v.z = ov[2 * k + 1];
      v.w = buf[r3 * 256 + ((jo3 - r3) & 255)];
    } else {      // even-I at m=0,2; odd-I at m=1,3
      int jo0 = jb, jo2 = jb + 2;
      int r0 = ((i + jo0) & 255) >> 1;
      int r2 = ((i + jo2) & 255) >> 1;
      v.x = buf[r0 * 256 + ((jo0 - r0) & 255)];
      v.y = ov[2 * k];
      v.z = buf[r2 * 256 + ((jo2 - r2) & 255)];
      v.w = ov[2 * k + 1];
    }
    op4[t] = v;
  }
}

extern "C" void kernel_launch(void* const* d_in, const int* in_sizes, int n_in,
                              void* d_out, int out_size, void* d_ws, size_t ws_size,
                              hipStream_t stream) {
  const float* y0 = (const float*)d_in[0];
  const float* y1 = (const float*)d_in[1];
  const float* y2 = (const float*)d_in[2];
  const float* y3 = (const float*)d_in[3];
  float* outp = (float*)d_out;
  (void)d_ws; (void)ws_size;  // no HBM intermediate anymore

  fused_kernel<<<256, 1024, 0, stream>>>(y0, y1, y2, y3, outp);
}